// Round 1
// baseline (882.741 us; speedup 1.0000x reference)
//
#include <hip/hip_runtime.h>

#define B_ 8
#define V_ 2048
#define D_ 3
#define M_ (B_*V_)   // 16384 rows

// ---------------------------------------------------------------------------
// K1: transpose x [B,D,V] -> x0 [B,V,D]; also seed XK (packed cheby basis,
// feature index = fin*6 + k) at k=0.
// ---------------------------------------------------------------------------
__global__ __launch_bounds__(256) void k_transpose(const float* __restrict__ x,
    float* __restrict__ x0, float* __restrict__ XK) {
  int i = blockIdx.x * 256 + threadIdx.x;
  if (i >= B_*V_*D_) return;
  int f = i % D_;
  int v = (i / D_) % V_;
  int b = i / (D_*V_);
  float val = x[((size_t)b*D_ + f)*V_ + v];
  x0[i] = val;
  XK[((size_t)b*V_ + v)*18 + f*6 + 0] = val;
}

// ---------------------------------------------------------------------------
// K2: cheby1 recurrence step (3 features):
//   xn[b][r][f] = alpha * sum_u L[b][r][u]*xc[b][u][f] - beta * xp[b][r][f]
// wave-per-row; xc[b] (24KB) cached in LDS, stride-3 access -> conflict-free.
// Also writes packed XK at slot kidx.
// ---------------------------------------------------------------------------
__global__ __launch_bounds__(256) void k_cheby1(const float* __restrict__ L,
    const float* __restrict__ xc, const float* __restrict__ xp,
    float* __restrict__ xn, float* __restrict__ XK,
    float alpha, float beta, int kidx) {
  __shared__ float sx[V_*D_];  // 24 KB
  int b  = blockIdx.x / (V_/32);
  int r0 = (blockIdx.x % (V_/32)) * 32;
  const float* xcb = xc + (size_t)b*V_*D_;
  for (int i = threadIdx.x; i < V_*D_; i += 256) sx[i] = xcb[i];
  __syncthreads();
  int wave = threadIdx.x >> 6, lane = threadIdx.x & 63;
  for (int rr = wave; rr < 32; rr += 4) {
    int r = r0 + rr;
    const float* Lrow = L + ((size_t)b*V_ + r)*V_;
    float a0 = 0.f, a1 = 0.f, a2 = 0.f;
    #pragma unroll 8
    for (int u = lane; u < V_; u += 64) {
      float lv = Lrow[u];
      a0 = fmaf(lv, sx[u*3+0], a0);
      a1 = fmaf(lv, sx[u*3+1], a1);
      a2 = fmaf(lv, sx[u*3+2], a2);
    }
    #pragma unroll
    for (int off = 32; off > 0; off >>= 1) {
      a0 += __shfl_down(a0, off);
      a1 += __shfl_down(a1, off);
      a2 += __shfl_down(a2, off);
    }
    if (lane == 0) {
      size_t base = ((size_t)b*V_ + r)*3;
      float v0 = alpha*a0, v1 = alpha*a1, v2 = alpha*a2;
      if (beta != 0.f) {
        v0 -= beta*xp[base+0];
        v1 -= beta*xp[base+1];
        v2 -= beta*xp[base+2];
      }
      xn[base+0] = v0; xn[base+1] = v1; xn[base+2] = v2;
      size_t xkb = ((size_t)b*V_ + r)*18 + kidx;
      XK[xkb + 0*6] = v0;
      XK[xkb + 1*6] = v1;
      XK[xkb + 2*6] = v2;
    }
  }
}

// ---------------------------------------------------------------------------
// K4: cheby2 recurrence step (64 features), fp32 tiled GEMM:
//   Zn[b][r][n] = alpha * sum_u L[b][r][u]*Zc[b][u][n] - beta * Zp[b][r][n]
// Tile 32 rows x 64 cols, K-tile 16, double-buffered LDS + register prefetch,
// one barrier per K-tile. Also writes packed ZK (stride 320, col*5 + kidx).
// ---------------------------------------------------------------------------
__global__ __launch_bounds__(256) void k_cheby2(const float* __restrict__ L,
    const float* __restrict__ Zc, const float* __restrict__ Zp,
    float* __restrict__ Zn, float* __restrict__ ZK,
    float alpha, float beta, int kidx) {
  __shared__ float sA[2][16][36];  // [kk][m], padded
  __shared__ float sB[2][16][68];  // [kk][n], padded (row 272B, 16B aligned)
  int b  = blockIdx.x / (V_/32);
  int r0 = (blockIdx.x % (V_/32)) * 32;
  const float* Lb = L  + (size_t)b*V_*V_;
  const float* Zb = Zc + (size_t)b*V_*64;
  int tid = threadIdx.x;
  int tx = tid & 15, ty = tid >> 4;      // compute map: rows ty*2+i, cols tx*4+j
  int lk = tid & 15, lm = tid >> 4;      // A-load map
  int bn = tid & 63, bk = tid >> 6;      // B-load map
  float acc[2][4] = {};

  auto compute = [&](int bf) {
    #pragma unroll
    for (int kk = 0; kk < 16; kk++) {
      float a0 = sA[bf][kk][ty*2+0];
      float a1 = sA[bf][kk][ty*2+1];
      float4 bv = *(const float4*)&sB[bf][kk][tx*4];
      float b4[4] = {bv.x, bv.y, bv.z, bv.w};
      #pragma unroll
      for (int j = 0; j < 4; j++) {
        acc[0][j] = fmaf(a0, b4[j], acc[0][j]);
        acc[1][j] = fmaf(a1, b4[j], acc[1][j]);
      }
    }
  };

  // preload tile 0
  sA[0][lk][lm]      = Lb[(size_t)(r0 + lm)*V_ + lk];
  sA[0][lk][lm + 16] = Lb[(size_t)(r0 + lm + 16)*V_ + lk];
  #pragma unroll
  for (int i = 0; i < 4; i++)
    sB[0][bk + i*4][bn] = Zb[(size_t)(bk + i*4)*64 + bn];
  __syncthreads();

  int buf = 0;
  for (int k0 = 16; k0 < V_; k0 += 16) {
    float ra0 = Lb[(size_t)(r0 + lm)*V_ + k0 + lk];
    float ra1 = Lb[(size_t)(r0 + lm + 16)*V_ + k0 + lk];
    float rb[4];
    #pragma unroll
    for (int i = 0; i < 4; i++)
      rb[i] = Zb[(size_t)(k0 + bk + i*4)*64 + bn];
    compute(buf);
    int nbuf = buf ^ 1;
    sA[nbuf][lk][lm]      = ra0;
    sA[nbuf][lk][lm + 16] = ra1;
    #pragma unroll
    for (int i = 0; i < 4; i++)
      sB[nbuf][bk + i*4][bn] = rb[i];
    __syncthreads();
    buf = nbuf;
  }
  compute(buf);

  #pragma unroll
  for (int i = 0; i < 2; i++) {
    int r = r0 + ty*2 + i;
    size_t rowb = (size_t)b*V_ + r;
    float vals[4];
    #pragma unroll
    for (int j = 0; j < 4; j++) vals[j] = alpha * acc[i][j];
    if (beta != 0.f) {
      const float* zp = Zp + rowb*64 + tx*4;
      #pragma unroll
      for (int j = 0; j < 4; j++) vals[j] -= beta * zp[j];
    }
    float4 st = {vals[0], vals[1], vals[2], vals[3]};
    *(float4*)&Zn[rowb*64 + tx*4] = st;
    #pragma unroll
    for (int j = 0; j < 4; j++)
      ZK[rowb*320 + (size_t)(tx*4 + j)*5 + kidx] = vals[j];
  }
}

// ---------------------------------------------------------------------------
// K3/K5/K6/K7: C[M,N] = relu(A[M,K] @ W[N,K]^T + bias), M=16384 fixed.
// Tile 64x64, K-tile 16 (bounds-checked for K=18/320/128/512), double-buffered
// LDS + register prefetch. Optional packed secondary write (for y1 -> ZK k=0).
// ---------------------------------------------------------------------------
__global__ __launch_bounds__(256) void k_gemm_fc(const float* __restrict__ A,
    const float* __restrict__ W, const float* __restrict__ bias,
    float* __restrict__ C, int N, int K,
    float* __restrict__ pack, int packStride, int packMul, int packOff) {
  __shared__ float sA[2][16][68];
  __shared__ float sB[2][16][68];
  int bm = blockIdx.x % (M_/64);
  int bn = blockIdx.x / (M_/64);
  int row0 = bm * 64, col0 = bn * 64;
  int tid = threadIdx.x;
  int tx = tid & 15, ty = tid >> 4;
  int lk = tid & 15, lm = tid >> 4;
  float acc[4][4] = {};

  auto compute = [&](int bf) {
    #pragma unroll
    for (int kk = 0; kk < 16; kk++) {
      float4 av = *(const float4*)&sA[bf][kk][ty*4];
      float4 bv = *(const float4*)&sB[bf][kk][tx*4];
      float a4[4] = {av.x, av.y, av.z, av.w};
      float b4[4] = {bv.x, bv.y, bv.z, bv.w};
      #pragma unroll
      for (int i = 0; i < 4; i++)
        #pragma unroll
        for (int j = 0; j < 4; j++)
          acc[i][j] = fmaf(a4[i], b4[j], acc[i][j]);
    }
  };

  // preload tile 0
  #pragma unroll
  for (int i = 0; i < 4; i++) {
    int m = lm + i*16;
    bool ok = lk < K;
    sA[0][lk][m] = ok ? A[(size_t)(row0+m)*K + lk] : 0.f;
    sB[0][lk][m] = ok ? W[(size_t)(col0+m)*K + lk] : 0.f;
  }
  __syncthreads();

  int buf = 0;
  int ntiles = (K + 15) / 16;
  for (int t = 1; t < ntiles; t++) {
    int k0 = t * 16;
    float ra[4], rb[4];
    bool ok = (k0 + lk) < K;
    #pragma unroll
    for (int i = 0; i < 4; i++) {
      int m = lm + i*16;
      ra[i] = ok ? A[(size_t)(row0+m)*K + k0 + lk] : 0.f;
      rb[i] = ok ? W[(size_t)(col0+m)*K + k0 + lk] : 0.f;
    }
    compute(buf);
    int nbuf = buf ^ 1;
    #pragma unroll
    for (int i = 0; i < 4; i++) {
      int m = lm + i*16;
      sA[nbuf][lk][m] = ra[i];
      sB[nbuf][lk][m] = rb[i];
    }
    __syncthreads();
    buf = nbuf;
  }
  compute(buf);

  #pragma unroll
  for (int i = 0; i < 4; i++) {
    int r = row0 + ty*4 + i;
    float vals[4];
    #pragma unroll
    for (int j = 0; j < 4; j++) {
      int c = col0 + tx*4 + j;
      float v = acc[i][j] + bias[c];
      vals[j] = v > 0.f ? v : 0.f;
    }
    float4 st = {vals[0], vals[1], vals[2], vals[3]};
    *(float4*)&C[(size_t)r*N + col0 + tx*4] = st;
    if (pack != nullptr) {
      #pragma unroll
      for (int j = 0; j < 4; j++)
        pack[(size_t)r*packStride + (size_t)(col0 + tx*4 + j)*packMul + packOff]
          = vals[j];
    }
  }
}

// ---------------------------------------------------------------------------
extern "C" void kernel_launch(void* const* d_in, const int* in_sizes, int n_in,
                              void* d_out, int out_size, void* d_ws, size_t ws_size,
                              hipStream_t stream) {
  const float* x   = (const float*)d_in[0];
  const float* L   = (const float*)d_in[1];
  const float* w1  = (const float*)d_in[2];
  const float* b1  = (const float*)d_in[3];
  const float* w2  = (const float*)d_in[4];
  const float* b2  = (const float*)d_in[5];
  const float* fw1 = (const float*)d_in[6];
  const float* fb1 = (const float*)d_in[7];
  const float* fw2 = (const float*)d_in[8];
  const float* fb2 = (const float*)d_in[9];
  float* out = (float*)d_out;

  float* p  = (float*)d_ws;
  float* xa = p;  p += (size_t)B_*V_*D_;
  float* xb = p;  p += (size_t)B_*V_*D_;
  float* xc = p;  p += (size_t)B_*V_*D_;
  float* XK = p;  p += (size_t)M_*18;
  float* y1 = p;  p += (size_t)M_*64;    // doubles as z-ping-pong slot 0
  float* zb = p;  p += (size_t)M_*64;
  float* zc = p;  p += (size_t)M_*64;
  float* ZK = p;  p += (size_t)M_*320;
  float* y2 = p;  p += (size_t)M_*128;
  float* h1 = p;  p += (size_t)M_*512;

  dim3 blk(256);

  k_transpose<<<(B_*V_*D_ + 255)/256, blk, 0, stream>>>(x, xa, XK);

  // cheby1: x0=xa, x1=xb, x2=xc, x3=xa, x4=xb, x5=xc
  k_cheby1<<<512, blk, 0, stream>>>(L, xa, xa, xb, XK, 1.f, 0.f, 1);
  k_cheby1<<<512, blk, 0, stream>>>(L, xb, xa, xc, XK, 2.f, 1.f, 2);
  k_cheby1<<<512, blk, 0, stream>>>(L, xc, xb, xa, XK, 2.f, 1.f, 3);
  k_cheby1<<<512, blk, 0, stream>>>(L, xa, xc, xb, XK, 2.f, 1.f, 4);
  k_cheby1<<<512, blk, 0, stream>>>(L, xb, xa, xc, XK, 2.f, 1.f, 5);

  // y1 = relu(XK @ w1^T + b1); pack z0 into ZK slot 0
  k_gemm_fc<<<256, blk, 0, stream>>>(XK, w1, b1, y1, 64, 18, ZK, 320, 5, 0);

  // cheby2: z0=y1, z1=zb, z2=zc, z3=y1, z4=zb
  k_cheby2<<<512, blk, 0, stream>>>(L, y1, y1, zb, ZK, 1.f, 0.f, 1);
  k_cheby2<<<512, blk, 0, stream>>>(L, zb, y1, zc, ZK, 2.f, 1.f, 2);
  k_cheby2<<<512, blk, 0, stream>>>(L, zc, zb, y1, ZK, 2.f, 1.f, 3);
  k_cheby2<<<512, blk, 0, stream>>>(L, y1, zc, zb, ZK, 2.f, 1.f, 4);

  // y2 = relu(ZK @ w2^T + b2)
  k_gemm_fc<<<512, blk, 0, stream>>>(ZK, w2, b2, y2, 128, 320,
                                     nullptr, 0, 0, 0);
  // h1 = relu(y2 @ fw1^T + fb1)
  k_gemm_fc<<<2048, blk, 0, stream>>>(y2, fw1, fb1, h1, 512, 128,
                                      nullptr, 0, 0, 0);
  // out = relu(h1 @ fw2^T + fb2)
  k_gemm_fc<<<1024, blk, 0, stream>>>(h1, fw2, fb2, out, 256, 512,
                                      nullptr, 0, 0, 0);
}

// Round 2
// 671.312 us; speedup vs baseline: 1.3149x; 1.3149x over previous
//
#include <hip/hip_runtime.h>

#define B_ 8
#define V_ 2048
#define D_ 3
#define M_ (B_*V_)   // 16384 rows

typedef __attribute__((ext_vector_type(8))) short short8;
typedef __attribute__((ext_vector_type(4))) float f32x4;

__device__ inline void async_copy16(const void* g, void* lds) {
  __builtin_amdgcn_global_load_lds(
      (const __attribute__((address_space(1))) unsigned int*)g,
      (__attribute__((address_space(3))) unsigned int*)lds, 16, 0, 0);
}

// ---------------------------------------------------------------------------
// K1: transpose x [B,D,V] -> x0 [B,V,D]; seed XK (packed cheby, fin*6+k) k=0.
// ---------------------------------------------------------------------------
__global__ __launch_bounds__(256) void k_transpose(const float* __restrict__ x,
    float* __restrict__ x0, float* __restrict__ XK) {
  int i = blockIdx.x * 256 + threadIdx.x;
  if (i >= B_*V_*D_) return;
  int f = i % D_;
  int v = (i / D_) % V_;
  int b = i / (D_*V_);
  float val = x[((size_t)b*D_ + f)*V_ + v];
  x0[i] = val;
  XK[((size_t)b*V_ + v)*18 + f*6 + 0] = val;
}

// ---------------------------------------------------------------------------
// K2: cheby1 recurrence step (3 features), wave-per-row, x in LDS.
// ---------------------------------------------------------------------------
__global__ __launch_bounds__(256) void k_cheby1(const float* __restrict__ L,
    const float* __restrict__ xc, const float* __restrict__ xp,
    float* __restrict__ xn, float* __restrict__ XK,
    float alpha, float beta, int kidx) {
  __shared__ float sx[V_*D_];  // 24 KB
  int b  = blockIdx.x / (V_/32);
  int r0 = (blockIdx.x % (V_/32)) * 32;
  const float* xcb = xc + (size_t)b*V_*D_;
  for (int i = threadIdx.x; i < V_*D_; i += 256) sx[i] = xcb[i];
  __syncthreads();
  int wave = threadIdx.x >> 6, lane = threadIdx.x & 63;
  for (int rr = wave; rr < 32; rr += 4) {
    int r = r0 + rr;
    const float* Lrow = L + ((size_t)b*V_ + r)*V_;
    float a0 = 0.f, a1 = 0.f, a2 = 0.f;
    #pragma unroll 8
    for (int u = lane; u < V_; u += 64) {
      float lv = Lrow[u];
      a0 = fmaf(lv, sx[u*3+0], a0);
      a1 = fmaf(lv, sx[u*3+1], a1);
      a2 = fmaf(lv, sx[u*3+2], a2);
    }
    #pragma unroll
    for (int off = 32; off > 0; off >>= 1) {
      a0 += __shfl_down(a0, off);
      a1 += __shfl_down(a1, off);
      a2 += __shfl_down(a2, off);
    }
    if (lane == 0) {
      size_t base = ((size_t)b*V_ + r)*3;
      float v0 = alpha*a0, v1 = alpha*a1, v2 = alpha*a2;
      if (beta != 0.f) {
        v0 -= beta*xp[base+0];
        v1 -= beta*xp[base+1];
        v2 -= beta*xp[base+2];
      }
      xn[base+0] = v0; xn[base+1] = v1; xn[base+2] = v2;
      size_t xkb = ((size_t)b*V_ + r)*18 + kidx;
      XK[xkb + 0*6] = v0;
      XK[xkb + 1*6] = v1;
      XK[xkb + 2*6] = v2;
    }
  }
}

// ---------------------------------------------------------------------------
// k_split_t: z [B,V,64] fp32 -> transposed bf16 hi/lo  Th/Tl [B,64,V]
// ---------------------------------------------------------------------------
__global__ __launch_bounds__(256) void k_split_t(const float* __restrict__ Z,
    short* __restrict__ Th, short* __restrict__ Tl) {
  __shared__ float t[64][65];
  int b  = blockIdx.x >> 5;
  int r0 = (blockIdx.x & 31) * 64;
  const float* Zb = Z + ((size_t)b*V_ + r0)*64;
  #pragma unroll 4
  for (int i = 0; i < 16; i++) {
    int idx = i*256 + threadIdx.x;
    int r = idx >> 6, n = idx & 63;
    t[r][n] = Zb[(size_t)r*64 + n];
  }
  __syncthreads();
  #pragma unroll 4
  for (int i = 0; i < 16; i++) {
    int idx = i*256 + threadIdx.x;
    int n = idx >> 6, r = idx & 63;
    float v = t[r][n];
    unsigned u  = __float_as_uint(v);
    unsigned hb = u & 0xFFFF0000u;
    float d = v - __uint_as_float(hb);
    size_t o = ((size_t)b*64 + n)*V_ + r0 + r;
    Th[o] = (short)(hb >> 16);
    Tl[o] = (short)(__float_as_uint(d) >> 16);
  }
}

// ---------------------------------------------------------------------------
// k_cheby2_mfma: Zn[b,r,n] = alpha * sum_u L[b,r,u] * z[b,u,n] - beta*Zp[b,r,n]
// z supplied as transposed bf16 hi/lo (Zth/Ztl, [b,64,V]).  Split-bf16 MFMA:
// acc += Ah*Bh + Ah*Bl + Al*Bh  (A = L tile, converted hi/lo on the fly).
// Tile 32r x 64n, BK=64, m97-style global_load_lds staging with XOR chunk
// swizzle (global source swizzled, LDS contiguous; frag reads 2-way max).
// Epilogue writes Zn fp32, packed ZK slot kidx, and next-step hi/lo transposed.
// ---------------------------------------------------------------------------
__global__ __launch_bounds__(256) void k_cheby2_mfma(const float* __restrict__ L,
    const short* __restrict__ Zth, const short* __restrict__ Ztl,
    const float* __restrict__ Zp,
    float* __restrict__ Zn, float* __restrict__ ZK,
    short* __restrict__ Znth, short* __restrict__ Zntl,
    float alpha, float beta, int kidx) {
  __shared__ float sA[32*64];    // L tile  [r][k], chunk-swizzled, 8 KB
  __shared__ short sBh[64*64];   // Zt hi   [n][k], chunk-swizzled, 8 KB
  __shared__ short sBl[64*64];   // Zt lo   [n][k], chunk-swizzled, 8 KB

  int b  = blockIdx.x >> 6;
  int r0 = (blockIdx.x & 63) * 32;
  const float* Lb   = L   + (size_t)b*V_*V_;
  const short* Zthb = Zth + (size_t)b*64*V_;
  const short* Ztlb = Ztl + (size_t)b*64*V_;

  int tid  = threadIdx.x;
  int w    = tid >> 6;           // wave 0..3
  int lane = tid & 63;
  int lm   = lane & 15;
  int quad = lane >> 4;
  int h     = (w & 1) * 16;      // wave row-half
  int cbase = (w >> 1) * 32;     // wave col-half

  const f32x4*  sAv  = (const f32x4*)sA;
  const short8* sBhv = (const short8*)sBh;
  const short8* sBlv = (const short8*)sBl;

  f32x4 acc0 = {0.f,0.f,0.f,0.f};
  f32x4 acc1 = {0.f,0.f,0.f,0.f};

  for (int s = 0; s < V_/64; s++) {
    int k0 = s * 64;
    if (s) __syncthreads();
    // stage loads (global_load_lds, 16B, swizzled global source)
    #pragma unroll
    for (int t = 0; t < 2; t++) {
      int f = t*256 + tid;
      int r = f >> 4, cc = f & 15;
      int c = cc ^ (r & 15);
      async_copy16(Lb + (size_t)(r0 + r)*V_ + k0 + c*4, &sA[f*4]);
    }
    #pragma unroll
    for (int t = 0; t < 2; t++) {
      int f = t*256 + tid;
      int n = f >> 3, cc = f & 7;
      int c = cc ^ (n & 7);
      async_copy16(Zthb + (size_t)n*V_ + k0 + c*8, &sBh[f*8]);
      async_copy16(Ztlb + (size_t)n*V_ + k0 + c*8, &sBl[f*8]);
    }
    __syncthreads();

    #pragma unroll
    for (int ks = 0; ks < 2; ks++) {
      int koff = ks * 32;
      // A fragment: 8 fp32 -> hi/lo bf16
      int r = h + lm;
      int c0 = (koff >> 2) + 2*quad;
      f32x4 a0 = sAv[r*16 + (c0 ^ (r & 15))];
      f32x4 a1 = sAv[r*16 + ((c0 + 1) ^ (r & 15))];
      float av[8] = {a0.x, a0.y, a0.z, a0.w, a1.x, a1.y, a1.z, a1.w};
      short8 ah, al;
      #pragma unroll
      for (int j = 0; j < 8; j++) {
        unsigned u  = __float_as_uint(av[j]);
        unsigned hb = u & 0xFFFF0000u;
        float d = av[j] - __uint_as_float(hb);
        ah[j] = (short)(hb >> 16);
        al[j] = (short)(__float_as_uint(d) >> 16);
      }
      int cb = (koff >> 3) + quad;
      {
        int n = cbase + lm;
        short8 bh = sBhv[n*8 + (cb ^ (n & 7))];
        short8 bl = sBlv[n*8 + (cb ^ (n & 7))];
        acc0 = __builtin_amdgcn_mfma_f32_16x16x32_bf16(ah, bh, acc0, 0, 0, 0);
        acc0 = __builtin_amdgcn_mfma_f32_16x16x32_bf16(ah, bl, acc0, 0, 0, 0);
        acc0 = __builtin_amdgcn_mfma_f32_16x16x32_bf16(al, bh, acc0, 0, 0, 0);
      }
      {
        int n = cbase + 16 + lm;
        short8 bh = sBhv[n*8 + (cb ^ (n & 7))];
        short8 bl = sBlv[n*8 + (cb ^ (n & 7))];
        acc1 = __builtin_amdgcn_mfma_f32_16x16x32_bf16(ah, bh, acc1, 0, 0, 0);
        acc1 = __builtin_amdgcn_mfma_f32_16x16x32_bf16(ah, bl, acc1, 0, 0, 0);
        acc1 = __builtin_amdgcn_mfma_f32_16x16x32_bf16(al, bh, acc1, 0, 0, 0);
      }
    }
  }

  // epilogue: C/D layout col=lane&15, row=quad*4+reg
  #pragma unroll
  for (int ct = 0; ct < 2; ct++) {
    f32x4 a = ct ? acc1 : acc0;
    int n = cbase + ct*16 + lm;
    #pragma unroll
    for (int i = 0; i < 4; i++) {
      int r = r0 + h + quad*4 + i;
      size_t rowb = (size_t)b*V_ + r;
      float v = alpha * a[i];
      if (beta != 0.f) v -= beta * Zp[rowb*64 + n];
      Zn[rowb*64 + n] = v;
      ZK[rowb*320 + (size_t)n*5 + kidx] = v;
      unsigned u  = __float_as_uint(v);
      unsigned hb = u & 0xFFFF0000u;
      float d = v - __uint_as_float(hb);
      size_t o = ((size_t)b*64 + n)*V_ + r;
      Znth[o] = (short)(hb >> 16);
      Zntl[o] = (short)(__float_as_uint(d) >> 16);
    }
  }
}

// ---------------------------------------------------------------------------
// FC GEMMs: C[M,N] = relu(A[M,K] @ W[N,K]^T + bias), fp32 tiled, 64x64 tile.
// ---------------------------------------------------------------------------
__global__ __launch_bounds__(256) void k_gemm_fc(const float* __restrict__ A,
    const float* __restrict__ W, const float* __restrict__ bias,
    float* __restrict__ C, int N, int K,
    float* __restrict__ pack, int packStride, int packMul, int packOff) {
  __shared__ float sA[2][16][68];
  __shared__ float sB[2][16][68];
  int bm = blockIdx.x % (M_/64);
  int bn = blockIdx.x / (M_/64);
  int row0 = bm * 64, col0 = bn * 64;
  int tid = threadIdx.x;
  int tx = tid & 15, ty = tid >> 4;
  int lk = tid & 15, lm = tid >> 4;
  float acc[4][4] = {};

  auto compute = [&](int bf) {
    #pragma unroll
    for (int kk = 0; kk < 16; kk++) {
      float4 av = *(const float4*)&sA[bf][kk][ty*4];
      float4 bv = *(const float4*)&sB[bf][kk][tx*4];
      float a4[4] = {av.x, av.y, av.z, av.w};
      float b4[4] = {bv.x, bv.y, bv.z, bv.w};
      #pragma unroll
      for (int i = 0; i < 4; i++)
        #pragma unroll
        for (int j = 0; j < 4; j++)
          acc[i][j] = fmaf(a4[i], b4[j], acc[i][j]);
    }
  };

  #pragma unroll
  for (int i = 0; i < 4; i++) {
    int m = lm + i*16;
    bool ok = lk < K;
    sA[0][lk][m] = ok ? A[(size_t)(row0+m)*K + lk] : 0.f;
    sB[0][lk][m] = ok ? W[(size_t)(col0+m)*K + lk] : 0.f;
  }
  __syncthreads();

  int buf = 0;
  int ntiles = (K + 15) / 16;
  for (int t = 1; t < ntiles; t++) {
    int k0 = t * 16;
    float ra[4], rb[4];
    bool ok = (k0 + lk) < K;
    #pragma unroll
    for (int i = 0; i < 4; i++) {
      int m = lm + i*16;
      ra[i] = ok ? A[(size_t)(row0+m)*K + k0 + lk] : 0.f;
      rb[i] = ok ? W[(size_t)(col0+m)*K + k0 + lk] : 0.f;
    }
    compute(buf);
    int nbuf = buf ^ 1;
    #pragma unroll
    for (int i = 0; i < 4; i++) {
      int m = lm + i*16;
      sA[nbuf][lk][m] = ra[i];
      sB[nbuf][lk][m] = rb[i];
    }
    __syncthreads();
    buf = nbuf;
  }
  compute(buf);

  #pragma unroll
  for (int i = 0; i < 4; i++) {
    int r = row0 + ty*4 + i;
    float vals[4];
    #pragma unroll
    for (int j = 0; j < 4; j++) {
      int c = col0 + tx*4 + j;
      float v = acc[i][j] + bias[c];
      vals[j] = v > 0.f ? v : 0.f;
    }
    float4 st = {vals[0], vals[1], vals[2], vals[3]};
    *(float4*)&C[(size_t)r*N + col0 + tx*4] = st;
    if (pack != nullptr) {
      #pragma unroll
      for (int j = 0; j < 4; j++)
        pack[(size_t)r*packStride + (size_t)(col0 + tx*4 + j)*packMul + packOff]
          = vals[j];
    }
  }
}

// ---------------------------------------------------------------------------
extern "C" void kernel_launch(void* const* d_in, const int* in_sizes, int n_in,
                              void* d_out, int out_size, void* d_ws, size_t ws_size,
                              hipStream_t stream) {
  const float* x   = (const float*)d_in[0];
  const float* L   = (const float*)d_in[1];
  const float* w1  = (const float*)d_in[2];
  const float* b1  = (const float*)d_in[3];
  const float* w2  = (const float*)d_in[4];
  const float* b2  = (const float*)d_in[5];
  const float* fw1 = (const float*)d_in[6];
  const float* fb1 = (const float*)d_in[7];
  const float* fw2 = (const float*)d_in[8];
  const float* fb2 = (const float*)d_in[9];
  float* out = (float*)d_out;

  float* p  = (float*)d_ws;
  float* xa = p;  p += (size_t)B_*V_*D_;
  float* xb = p;  p += (size_t)B_*V_*D_;
  float* xc = p;  p += (size_t)B_*V_*D_;
  float* XK = p;  p += (size_t)M_*18;
  float* y1 = p;  p += (size_t)M_*64;
  float* zb = p;  p += (size_t)M_*64;
  float* zc = p;  p += (size_t)M_*64;
  float* ZK = p;  p += (size_t)M_*320;
  float* y2 = p;  p += (size_t)M_*128;
  float* h1 = p;  p += (size_t)M_*512;
  short* ZtAh = (short*)p;
  short* ZtAl = ZtAh + (size_t)M_*64;
  short* ZtBh = ZtAl + (size_t)M_*64;
  short* ZtBl = ZtBh + (size_t)M_*64;

  dim3 blk(256);

  k_transpose<<<(B_*V_*D_ + 255)/256, blk, 0, stream>>>(x, xa, XK);

  // cheby1: x0=xa, x1=xb, x2=xc, x3=xa, x4=xb, x5=xc
  k_cheby1<<<512, blk, 0, stream>>>(L, xa, xa, xb, XK, 1.f, 0.f, 1);
  k_cheby1<<<512, blk, 0, stream>>>(L, xb, xa, xc, XK, 2.f, 1.f, 2);
  k_cheby1<<<512, blk, 0, stream>>>(L, xc, xb, xa, XK, 2.f, 1.f, 3);
  k_cheby1<<<512, blk, 0, stream>>>(L, xa, xc, xb, XK, 2.f, 1.f, 4);
  k_cheby1<<<512, blk, 0, stream>>>(L, xb, xa, xc, XK, 2.f, 1.f, 5);

  // y1 = relu(XK @ w1^T + b1); pack z0 into ZK slot 0
  k_gemm_fc<<<256, blk, 0, stream>>>(XK, w1, b1, y1, 64, 18, ZK, 320, 5, 0);

  // z0 -> transposed bf16 hi/lo
  k_split_t<<<256, blk, 0, stream>>>(y1, ZtAh, ZtAl);

  // cheby2 (MFMA): z1=zb, z2=zc, z3->y1, z4->zb
  k_cheby2_mfma<<<512, blk, 0, stream>>>(L, ZtAh, ZtAl, y1, zb, ZK, ZtBh, ZtBl,
                                         1.f, 0.f, 1);
  k_cheby2_mfma<<<512, blk, 0, stream>>>(L, ZtBh, ZtBl, y1, zc, ZK, ZtAh, ZtAl,
                                         2.f, 1.f, 2);
  k_cheby2_mfma<<<512, blk, 0, stream>>>(L, ZtAh, ZtAl, zb, y1, ZK, ZtBh, ZtBl,
                                         2.f, 1.f, 3);
  k_cheby2_mfma<<<512, blk, 0, stream>>>(L, ZtBh, ZtBl, zc, zb, ZK, ZtAh, ZtAl,
                                         2.f, 1.f, 4);

  // y2 = relu(ZK @ w2^T + b2)
  k_gemm_fc<<<512, blk, 0, stream>>>(ZK, w2, b2, y2, 128, 320,
                                     nullptr, 0, 0, 0);
  // h1 = relu(y2 @ fw1^T + fb1)
  k_gemm_fc<<<2048, blk, 0, stream>>>(y2, fw1, fb1, h1, 512, 128,
                                      nullptr, 0, 0, 0);
  // out = relu(h1 @ fw2^T + fb2)
  k_gemm_fc<<<1024, blk, 0, stream>>>(h1, fw2, fb2, out, 256, 512,
                                      nullptr, 0, 0, 0);
}

// Round 3
// 594.671 us; speedup vs baseline: 1.4844x; 1.1289x over previous
//
#include <hip/hip_runtime.h>

#define B_ 8
#define V_ 2048
#define D_ 3
#define M_ (B_*V_)   // 16384 rows

typedef __attribute__((ext_vector_type(8))) short short8;
typedef __attribute__((ext_vector_type(4))) float f32x4;

__device__ inline void async_copy16(const void* g, void* lds) {
  __builtin_amdgcn_global_load_lds(
      (const __attribute__((address_space(1))) unsigned int*)g,
      (__attribute__((address_space(3))) unsigned int*)lds, 16, 0, 0);
}

__device__ inline void split_bf16(float v, short& hi, short& lo) {
  unsigned u  = __float_as_uint(v);
  unsigned hb = u & 0xFFFF0000u;
  float d = v - __uint_as_float(hb);
  hi = (short)(hb >> 16);
  lo = (short)(__float_as_uint(d) >> 16);
}

// ---------------------------------------------------------------------------
// k_zero: zero a region (float4-vectorized).  Used for XKh/XKl pad slots.
// ---------------------------------------------------------------------------
__global__ __launch_bounds__(256) void k_zero(float4* __restrict__ p, int n4) {
  int i = blockIdx.x * 256 + threadIdx.x;
  if (i < n4) p[i] = float4{0.f, 0.f, 0.f, 0.f};
}

// ---------------------------------------------------------------------------
// k_split_pad: W [N,K] fp32 -> Wh/Wl [N,Kpad] bf16 hi/lo (zero-padded K).
// ---------------------------------------------------------------------------
__global__ __launch_bounds__(256) void k_split_pad(const float* __restrict__ src,
    short* __restrict__ dh, short* __restrict__ dl, int N, int K, int Kpad) {
  int idx = blockIdx.x * 256 + threadIdx.x;
  if (idx >= N * Kpad) return;
  int n = idx / Kpad, k = idx - n * Kpad;
  float v = (k < K) ? src[(size_t)n*K + k] : 0.f;
  short hi, lo; split_bf16(v, hi, lo);
  dh[idx] = hi; dl[idx] = lo;
}

// ---------------------------------------------------------------------------
// K1: transpose x [B,D,V] -> x0 [B,V,D]; seed XKh/l (packed cheby, fin*6+k) k=0.
// ---------------------------------------------------------------------------
__global__ __launch_bounds__(256) void k_transpose(const float* __restrict__ x,
    float* __restrict__ x0, short* __restrict__ XKh, short* __restrict__ XKl) {
  int i = blockIdx.x * 256 + threadIdx.x;
  if (i >= B_*V_*D_) return;
  int f = i % D_;
  int v = (i / D_) % V_;
  int b = i / (D_*V_);
  float val = x[((size_t)b*D_ + f)*V_ + v];
  x0[i] = val;
  short hi, lo; split_bf16(val, hi, lo);
  size_t o = ((size_t)b*V_ + v)*64 + f*6;
  XKh[o] = hi; XKl[o] = lo;
}

// ---------------------------------------------------------------------------
// K2: cheby1 step (3 features): xn = alpha*(L@xc) - beta*xp, float4 L loads.
// x in LDS transposed sx[3][2048] -> conflict-free float4 reads.
// ---------------------------------------------------------------------------
__global__ __launch_bounds__(256) void k_cheby1(const float* __restrict__ L,
    const float* __restrict__ xc, const float* __restrict__ xp,
    float* __restrict__ xn, short* __restrict__ XKh, short* __restrict__ XKl,
    float alpha, float beta, int kidx) {
  __shared__ float sx[3][V_];  // 24 KB
  int b  = blockIdx.x >> 6;
  int r0 = (blockIdx.x & 63) * 32;
  const float* xcb = xc + (size_t)b*V_*D_;
  for (int i = threadIdx.x; i < V_*D_; i += 256) {
    int u = i / 3, f = i - u*3;
    sx[f][u] = xcb[i];
  }
  __syncthreads();
  int w = threadIdx.x >> 6, lane = threadIdx.x & 63;
  const float4* X0 = (const float4*)sx[0];
  const float4* X1 = (const float4*)sx[1];
  const float4* X2 = (const float4*)sx[2];
  for (int pass = 0; pass < 4; pass++) {
    int rA = r0 + pass*8 + w*2;
    int rB = rA + 1;
    const float4* LA = (const float4*)(L + ((size_t)b*V_ + rA)*V_);
    const float4* LB = (const float4*)(L + ((size_t)b*V_ + rB)*V_);
    float a0=0.f,a1=0.f,a2=0.f,b0=0.f,b1=0.f,b2=0.f;
    #pragma unroll
    for (int it = 0; it < 8; it++) {
      int u4 = it*64 + lane;
      float4 la = LA[u4], lb = LB[u4];
      float4 x0 = X0[u4], x1 = X1[u4], x2 = X2[u4];
      a0 = fmaf(la.x,x0.x,fmaf(la.y,x0.y,fmaf(la.z,x0.z,fmaf(la.w,x0.w,a0))));
      a1 = fmaf(la.x,x1.x,fmaf(la.y,x1.y,fmaf(la.z,x1.z,fmaf(la.w,x1.w,a1))));
      a2 = fmaf(la.x,x2.x,fmaf(la.y,x2.y,fmaf(la.z,x2.z,fmaf(la.w,x2.w,a2))));
      b0 = fmaf(lb.x,x0.x,fmaf(lb.y,x0.y,fmaf(lb.z,x0.z,fmaf(lb.w,x0.w,b0))));
      b1 = fmaf(lb.x,x1.x,fmaf(lb.y,x1.y,fmaf(lb.z,x1.z,fmaf(lb.w,x1.w,b1))));
      b2 = fmaf(lb.x,x2.x,fmaf(lb.y,x2.y,fmaf(lb.z,x2.z,fmaf(lb.w,x2.w,b2))));
    }
    #pragma unroll
    for (int off = 32; off > 0; off >>= 1) {
      a0 += __shfl_down(a0, off); a1 += __shfl_down(a1, off);
      a2 += __shfl_down(a2, off); b0 += __shfl_down(b0, off);
      b1 += __shfl_down(b1, off); b2 += __shfl_down(b2, off);
    }
    if (lane == 0) {
      float vA[3] = {alpha*a0, alpha*a1, alpha*a2};
      float vB[3] = {alpha*b0, alpha*b1, alpha*b2};
      size_t baseA = ((size_t)b*V_ + rA)*3;
      size_t baseB = ((size_t)b*V_ + rB)*3;
      if (beta != 0.f) {
        #pragma unroll
        for (int f = 0; f < 3; f++) {
          vA[f] -= beta * xp[baseA + f];
          vB[f] -= beta * xp[baseB + f];
        }
      }
      #pragma unroll
      for (int f = 0; f < 3; f++) {
        xn[baseA + f] = vA[f];
        xn[baseB + f] = vB[f];
        short hi, lo;
        split_bf16(vA[f], hi, lo);
        size_t oA = ((size_t)b*V_ + rA)*64 + f*6 + kidx;
        XKh[oA] = hi; XKl[oA] = lo;
        split_bf16(vB[f], hi, lo);
        size_t oB = ((size_t)b*V_ + rB)*64 + f*6 + kidx;
        XKh[oB] = hi; XKl[oB] = lo;
      }
    }
  }
}

// ---------------------------------------------------------------------------
// k_split_t: z [B,V,64] fp32 -> transposed bf16 hi/lo  Th/Tl [B,64,V]
// ---------------------------------------------------------------------------
__global__ __launch_bounds__(256) void k_split_t(const float* __restrict__ Z,
    short* __restrict__ Th, short* __restrict__ Tl) {
  __shared__ float t[64][65];
  int b  = blockIdx.x >> 5;
  int r0 = (blockIdx.x & 31) * 64;
  const float* Zb = Z + ((size_t)b*V_ + r0)*64;
  #pragma unroll 4
  for (int i = 0; i < 16; i++) {
    int idx = i*256 + threadIdx.x;
    int r = idx >> 6, n = idx & 63;
    t[r][n] = Zb[(size_t)r*64 + n];
  }
  __syncthreads();
  #pragma unroll 4
  for (int i = 0; i < 16; i++) {
    int idx = i*256 + threadIdx.x;
    int n = idx >> 6, r = idx & 63;
    short hi, lo; split_bf16(t[r][n], hi, lo);
    size_t o = ((size_t)b*64 + n)*V_ + r0 + r;
    Th[o] = hi; Tl[o] = lo;
  }
}

// ---------------------------------------------------------------------------
// k_cheby2_mfma: Zn = alpha*(L @ z) - beta*Zp ; split-bf16 MFMA.
// Epilogue: Zn fp32 ping-pong, ZKh/l bf16 pack (slot kidx), next hi/lo transposed.
// ---------------------------------------------------------------------------
__global__ __launch_bounds__(256) void k_cheby2_mfma(const float* __restrict__ L,
    const short* __restrict__ Zth, const short* __restrict__ Ztl,
    const float* __restrict__ Zp,
    float* __restrict__ Zn, short* __restrict__ ZKh, short* __restrict__ ZKl,
    short* __restrict__ Znth, short* __restrict__ Zntl,
    float alpha, float beta, int kidx) {
  __shared__ float sA[32*64];
  __shared__ short sBh[64*64];
  __shared__ short sBl[64*64];

  int b  = blockIdx.x >> 6;
  int r0 = (blockIdx.x & 63) * 32;
  const float* Lb   = L   + (size_t)b*V_*V_;
  const short* Zthb = Zth + (size_t)b*64*V_;
  const short* Ztlb = Ztl + (size_t)b*64*V_;

  int tid  = threadIdx.x;
  int w    = tid >> 6;
  int lane = tid & 63;
  int lm   = lane & 15;
  int quad = lane >> 4;
  int h     = (w & 1) * 16;
  int cbase = (w >> 1) * 32;

  const f32x4*  sAv  = (const f32x4*)sA;
  const short8* sBhv = (const short8*)sBh;
  const short8* sBlv = (const short8*)sBl;

  f32x4 acc0 = {0.f,0.f,0.f,0.f};
  f32x4 acc1 = {0.f,0.f,0.f,0.f};

  for (int s = 0; s < V_/64; s++) {
    int k0 = s * 64;
    if (s) __syncthreads();
    #pragma unroll
    for (int t = 0; t < 2; t++) {
      int f = t*256 + tid;
      int r = f >> 4, cc = f & 15;
      int c = cc ^ (r & 15);
      async_copy16(Lb + (size_t)(r0 + r)*V_ + k0 + c*4, &sA[f*4]);
    }
    #pragma unroll
    for (int t = 0; t < 2; t++) {
      int f = t*256 + tid;
      int n = f >> 3, cc = f & 7;
      int c = cc ^ (n & 7);
      async_copy16(Zthb + (size_t)n*V_ + k0 + c*8, &sBh[f*8]);
      async_copy16(Ztlb + (size_t)n*V_ + k0 + c*8, &sBl[f*8]);
    }
    __syncthreads();

    #pragma unroll
    for (int ks = 0; ks < 2; ks++) {
      int koff = ks * 32;
      int r = h + lm;
      int c0 = (koff >> 2) + 2*quad;
      f32x4 a0 = sAv[r*16 + (c0 ^ (r & 15))];
      f32x4 a1 = sAv[r*16 + ((c0 + 1) ^ (r & 15))];
      float av[8] = {a0.x, a0.y, a0.z, a0.w, a1.x, a1.y, a1.z, a1.w};
      short8 ah, al;
      #pragma unroll
      for (int j = 0; j < 8; j++) {
        short hi, lo; split_bf16(av[j], hi, lo);
        ah[j] = hi; al[j] = lo;
      }
      int cb = (koff >> 3) + quad;
      {
        int n = cbase + lm;
        short8 bh = sBhv[n*8 + (cb ^ (n & 7))];
        short8 bl = sBlv[n*8 + (cb ^ (n & 7))];
        acc0 = __builtin_amdgcn_mfma_f32_16x16x32_bf16(ah, bh, acc0, 0, 0, 0);
        acc0 = __builtin_amdgcn_mfma_f32_16x16x32_bf16(ah, bl, acc0, 0, 0, 0);
        acc0 = __builtin_amdgcn_mfma_f32_16x16x32_bf16(al, bh, acc0, 0, 0, 0);
      }
      {
        int n = cbase + 16 + lm;
        short8 bh = sBhv[n*8 + (cb ^ (n & 7))];
        short8 bl = sBlv[n*8 + (cb ^ (n & 7))];
        acc1 = __builtin_amdgcn_mfma_f32_16x16x32_bf16(ah, bh, acc1, 0, 0, 0);
        acc1 = __builtin_amdgcn_mfma_f32_16x16x32_bf16(ah, bl, acc1, 0, 0, 0);
        acc1 = __builtin_amdgcn_mfma_f32_16x16x32_bf16(al, bh, acc1, 0, 0, 0);
      }
    }
  }

  #pragma unroll
  for (int ct = 0; ct < 2; ct++) {
    f32x4 a = ct ? acc1 : acc0;
    int n = cbase + ct*16 + lm;
    #pragma unroll
    for (int i = 0; i < 4; i++) {
      int r = r0 + h + quad*4 + i;
      size_t rowb = (size_t)b*V_ + r;
      float v = alpha * a[i];
      if (beta != 0.f) v -= beta * Zp[rowb*64 + n];
      Zn[rowb*64 + n] = v;
      short hi, lo; split_bf16(v, hi, lo);
      size_t ok = rowb*320 + (size_t)n*5 + kidx;
      ZKh[ok] = hi; ZKl[ok] = lo;
      size_t o = ((size_t)b*64 + n)*V_ + r;
      Znth[o] = hi; Zntl[o] = lo;
    }
  }
}

// ---------------------------------------------------------------------------
// k_gemm_bf16: C[M,N] = relu(A[M,K] @ W[N,K]^T + bias), split-bf16 MFMA.
// A/W pre-split hi/lo bf16 row-major (K mult of 64). Block 64x64, 4 waves
// 2x2, wave 32x32. XOR chunk swizzle on global source; LDS contiguous.
// Outputs (any subset): Cf fp32 [M,N]; Ch/Cl bf16 [M,N]; Ph/Pl packed bf16.
// ---------------------------------------------------------------------------
__global__ __launch_bounds__(256) void k_gemm_bf16(
    const short* __restrict__ Ah, const short* __restrict__ Al,
    const short* __restrict__ Wh, const short* __restrict__ Wl,
    const float* __restrict__ bias, int N, int K,
    float* __restrict__ Cf, short* __restrict__ Ch, short* __restrict__ Cl,
    short* __restrict__ Ph, short* __restrict__ Pl,
    int packMul, int packStride) {
  __shared__ short sAh[64*64], sAl[64*64], sWh[64*64], sWl[64*64];  // 32 KB
  int bm = blockIdx.x & 255;       // M_/64 = 256
  int bn = blockIdx.x >> 8;
  int row0 = bm * 64, col0 = bn * 64;
  int tid = threadIdx.x, w = tid >> 6, lane = tid & 63;
  int lm = lane & 15, quad = lane >> 4;
  int wm = (w & 1) * 32, wn = (w >> 1) * 32;

  const short8* vAh = (const short8*)sAh;
  const short8* vAl = (const short8*)sAl;
  const short8* vWh = (const short8*)sWh;
  const short8* vWl = (const short8*)sWl;

  f32x4 acc[2][2] = {{{0.f,0.f,0.f,0.f},{0.f,0.f,0.f,0.f}},
                     {{0.f,0.f,0.f,0.f},{0.f,0.f,0.f,0.f}}};

  for (int k0 = 0; k0 < K; k0 += 64) {
    if (k0) __syncthreads();
    #pragma unroll
    for (int t = 0; t < 2; t++) {
      int f = t*256 + tid;
      int r = f >> 3, p = f & 7;
      int c = p ^ (r & 7);
      size_t goA = (size_t)(row0 + r)*K + k0 + c*8;
      size_t goW = (size_t)(col0 + r)*K + k0 + c*8;
      async_copy16(Ah + goA, &sAh[f*8]);
      async_copy16(Al + goA, &sAl[f*8]);
      async_copy16(Wh + goW, &sWh[f*8]);
      async_copy16(Wl + goW, &sWl[f*8]);
    }
    __syncthreads();

    #pragma unroll
    for (int ks = 0; ks < 2; ks++) {
      int kc = ks*4 + quad;
      short8 a_h[2], a_l[2], b_h[2], b_l[2];
      #pragma unroll
      for (int i = 0; i < 2; i++) {
        int m = wm + i*16 + lm;
        a_h[i] = vAh[m*8 + (kc ^ (m & 7))];
        a_l[i] = vAl[m*8 + (kc ^ (m & 7))];
      }
      #pragma unroll
      for (int j = 0; j < 2; j++) {
        int n = wn + j*16 + lm;
        b_h[j] = vWh[n*8 + (kc ^ (n & 7))];
        b_l[j] = vWl[n*8 + (kc ^ (n & 7))];
      }
      #pragma unroll
      for (int i = 0; i < 2; i++)
        #pragma unroll
        for (int j = 0; j < 2; j++) {
          acc[i][j] = __builtin_amdgcn_mfma_f32_16x16x32_bf16(a_h[i], b_h[j], acc[i][j], 0, 0, 0);
          acc[i][j] = __builtin_amdgcn_mfma_f32_16x16x32_bf16(a_h[i], b_l[j], acc[i][j], 0, 0, 0);
          acc[i][j] = __builtin_amdgcn_mfma_f32_16x16x32_bf16(a_l[i], b_h[j], acc[i][j], 0, 0, 0);
        }
    }
  }

  #pragma unroll
  for (int i = 0; i < 2; i++)
    #pragma unroll
    for (int j = 0; j < 2; j++) {
      int col = col0 + wn + j*16 + lm;
      float bj = bias[col];
      #pragma unroll
      for (int g = 0; g < 4; g++) {
        int row = row0 + wm + i*16 + quad*4 + g;
        float v = acc[i][j][g] + bj;
        v = v > 0.f ? v : 0.f;
        if (Cf) Cf[(size_t)row*N + col] = v;
        if (Ch) {
          short hi, lo; split_bf16(v, hi, lo);
          Ch[(size_t)row*N + col] = hi;
          Cl[(size_t)row*N + col] = lo;
        }
        if (Ph) {
          short hi, lo; split_bf16(v, hi, lo);
          size_t o = (size_t)row*packStride + (size_t)col*packMul;
          Ph[o] = hi; Pl[o] = lo;
        }
      }
    }
}

// ---------------------------------------------------------------------------
extern "C" void kernel_launch(void* const* d_in, const int* in_sizes, int n_in,
                              void* d_out, int out_size, void* d_ws, size_t ws_size,
                              hipStream_t stream) {
  const float* x   = (const float*)d_in[0];
  const float* L   = (const float*)d_in[1];
  const float* w1  = (const float*)d_in[2];
  const float* b1  = (const float*)d_in[3];
  const float* w2  = (const float*)d_in[4];
  const float* b2  = (const float*)d_in[5];
  const float* fw1 = (const float*)d_in[6];
  const float* fb1 = (const float*)d_in[7];
  const float* fw2 = (const float*)d_in[8];
  const float* fb2 = (const float*)d_in[9];
  float* out = (float*)d_out;

  float* p  = (float*)d_ws;
  float* xa = p;  p += (size_t)B_*V_*D_;
  float* xb = p;  p += (size_t)B_*V_*D_;
  float* xc = p;  p += (size_t)B_*V_*D_;
  float* y1 = p;  p += (size_t)M_*64;
  float* zb = p;  p += (size_t)M_*64;
  float* zc = p;  p += (size_t)M_*64;
  short* sp = (short*)p;
  short* ZKh = sp;  sp += (size_t)M_*320;
  short* ZKl = sp;  sp += (size_t)M_*320;
  short* y2h = sp;  sp += (size_t)M_*128;
  short* y2l = sp;  sp += (size_t)M_*128;
  short* h1h = sp;  sp += (size_t)M_*512;
  short* h1l = sp;  sp += (size_t)M_*512;
  short* ZtAh = sp; sp += (size_t)M_*64;
  short* ZtAl = sp; sp += (size_t)M_*64;
  short* ZtBh = sp; sp += (size_t)M_*64;
  short* ZtBl = sp; sp += (size_t)M_*64;
  short* w1h = sp;  sp += 64*64;
  short* w1l = sp;  sp += 64*64;
  short* w2h = sp;  sp += 128*320;
  short* w2l = sp;  sp += 128*320;
  short* fw1h = sp; sp += 512*128;
  short* fw1l = sp; sp += 512*128;
  short* fw2h = sp; sp += 256*512;
  short* fw2l = sp; sp += 256*512;
  // XKh/XKl aliased into h1h region (disjoint lifetime: XK consumed by y1-gemm
  // before h1-gemm writes h1h/l).
  short* XKh = h1h;
  short* XKl = h1h + (size_t)M_*64;

  dim3 blk(256);

  // zero XK (pads beyond slot 17 must be 0 every call; ws is re-poisoned)
  k_zero<<<1024, blk, 0, stream>>>((float4*)XKh, (M_*128) / 8);

  // weight splits (tiny)
  k_split_pad<<<(64*64+255)/256,   blk, 0, stream>>>(w1,  w1h,  w1l,  64, 18, 64);
  k_split_pad<<<(128*320+255)/256, blk, 0, stream>>>(w2,  w2h,  w2l,  128, 320, 320);
  k_split_pad<<<(512*128+255)/256, blk, 0, stream>>>(fw1, fw1h, fw1l, 512, 128, 128);
  k_split_pad<<<(256*512+255)/256, blk, 0, stream>>>(fw2, fw2h, fw2l, 256, 512, 512);

  k_transpose<<<(B_*V_*D_ + 255)/256, blk, 0, stream>>>(x, xa, XKh, XKl);

  // cheby1: x0=xa, x1=xb, x2=xc, x3=xa, x4=xb, x5=xc
  k_cheby1<<<512, blk, 0, stream>>>(L, xa, xa, xb, XKh, XKl, 1.f, 0.f, 1);
  k_cheby1<<<512, blk, 0, stream>>>(L, xb, xa, xc, XKh, XKl, 2.f, 1.f, 2);
  k_cheby1<<<512, blk, 0, stream>>>(L, xc, xb, xa, XKh, XKl, 2.f, 1.f, 3);
  k_cheby1<<<512, blk, 0, stream>>>(L, xa, xc, xb, XKh, XKl, 2.f, 1.f, 4);
  k_cheby1<<<512, blk, 0, stream>>>(L, xb, xa, xc, XKh, XKl, 2.f, 1.f, 5);

  // y1 = relu(XK @ w1^T + b1) -> y1 fp32 + ZK slot 0 pack
  k_gemm_bf16<<<256, blk, 0, stream>>>(XKh, XKl, w1h, w1l, b1, 64, 64,
                                       y1, nullptr, nullptr, ZKh, ZKl, 5, 320);

  // z0 -> transposed bf16 hi/lo
  k_split_t<<<256, blk, 0, stream>>>(y1, ZtAh, ZtAl);

  // cheby2 (MFMA): z1=zb, z2=zc, z3->y1, z4->zb
  k_cheby2_mfma<<<512, blk, 0, stream>>>(L, ZtAh, ZtAl, y1, zb, ZKh, ZKl,
                                         ZtBh, ZtBl, 1.f, 0.f, 1);
  k_cheby2_mfma<<<512, blk, 0, stream>>>(L, ZtBh, ZtBl, y1, zc, ZKh, ZKl,
                                         ZtAh, ZtAl, 2.f, 1.f, 2);
  k_cheby2_mfma<<<512, blk, 0, stream>>>(L, ZtAh, ZtAl, zb, y1, ZKh, ZKl,
                                         ZtBh, ZtBl, 2.f, 1.f, 3);
  k_cheby2_mfma<<<512, blk, 0, stream>>>(L, ZtBh, ZtBl, zc, zb, ZKh, ZKl,
                                         ZtAh, ZtAl, 2.f, 1.f, 4);

  // y2 = relu(ZK @ w2^T + b2) -> bf16 hi/lo
  k_gemm_bf16<<<512, blk, 0, stream>>>(ZKh, ZKl, w2h, w2l, b2, 128, 320,
                                       nullptr, y2h, y2l, nullptr, nullptr, 0, 0);
  // h1 = relu(y2 @ fw1^T + fb1) -> bf16 hi/lo  (overwrites XK alias; XK dead)
  k_gemm_bf16<<<2048, blk, 0, stream>>>(y2h, y2l, fw1h, fw1l, fb1, 512, 128,
                                        nullptr, h1h, h1l, nullptr, nullptr, 0, 0);
  // out = relu(h1 @ fw2^T + fb2) -> fp32
  k_gemm_bf16<<<1024, blk, 0, stream>>>(h1h, h1l, fw2h, fw2l, fb2, 256, 512,
                                        out, nullptr, nullptr, nullptr, nullptr, 0, 0);
}